// Round 7
// baseline (359.563 us; speedup 1.0000x reference)
//
#include <hip/hip_runtime.h>
#include <hip/hip_fp16.h>

// ---------------------------------------------------------------------------
// GCN forward: h1 = relu(GCNConv(x, W1, b1)); h2 = relu(GCNConv(h1, W2, b2));
// out = h2 @ W_lin + b_lin
// N=100000, E=3200000, F_in=128, H=16, F_out=128.
// edge_index arrives as int32 [2*E]: row 0 = src, row 1 = dst.
//
// R15 pipeline (memset + 5 kernels):
//   memset(deg) -> initcur (cur[b]=b*BCAP) -> partition (per-block LDS hist
//   -> dense run reservation, ONE global atomic per (block,bucket); ALSO
//   fire-and-forget global atomicAdd deg[dst] -- no return value, no latency
//   chain, 400KB L2-resident) -> xform1 (computes dinv=rsqrt(deg+1) in-kernel,
//   stores it, then g1 = fp16((x@W1)*dinv)) -> aggr1e -> aggr2e.
// R14 post-mortem: aggr kernels ran at 43% occupancy purely from grid
// imbalance (391 blocks / 256 CUs, 2 blocks/CU max -> makespan = 2 bucket-
// times, half the CUs idle in the tail). R15: NPB 256->128 => 782 blocks x
// 512 thr, ~17.5KB LDS -> 4 blocks/CU -> ALL blocks resident at once
// (capacity 1024 >= 782): no dispatch tail + 2x gather concurrency per CU.
// k_deg deleted (its 12.8MB pairs re-read + ~20us): deg folded into
// partition pass-1 as fire-and-forget global atomics (R13's failure was
// POSITION-RETURNING atomics + random 4B scatter; counting atomics have no
// dependent consumer and no write amplification).
// Fixed-point scale 2^18: quantization 3.8e-6/edge << fp16 4.9e-4; int sums
// exact & order-independent (deterministic). Overflow margin ~19x.
// ---------------------------------------------------------------------------

typedef int   v4i __attribute__((ext_vector_type(4)));
typedef float v4f __attribute__((ext_vector_type(4)));
typedef float v2f __attribute__((ext_vector_type(2)));

#define NPB        128    // nodes per bucket
#define NPB_SHIFT  7
#define NB_MAX     1024   // max buckets (N up to 131K)
#define BCAP       5632   // per-bucket pairs capacity (mean 4096, sigma~64, +24σ)
#define PART_TILE  8192   // edges per partition block
#define PART_THR   1024
#define PT_ITERS   (PART_TILE / 4 / PART_THR)   // = 2 quads/thread
#define FXSCALE    262144.0f          // 2^18
#define FXINV      (1.0f / 262144.0f)

// cur[b] = b*BCAP  (fixed bucket bases; no counting pass needed)
__global__ __launch_bounds__(NB_MAX) void k_initcur(int* __restrict__ cur) {
    cur[threadIdx.x] = threadIdx.x * BCAP;
}

// Partition edges into bucket-contiguous packed (src<<7 | dstlocal) runs,
// and histogram per-node degree via fire-and-forget global atomics.
__global__ __launch_bounds__(PART_THR) void k_partition(const int* __restrict__ ei,
                                                        int* __restrict__ cur,
                                                        int* __restrict__ pairs,
                                                        int* __restrict__ deg, int E) {
    __shared__ int h[NB_MAX];    // pass1: local hist; pass2: local cursor
    __shared__ int rb[NB_MAX];   // run base (absolute) per bucket
    int t = threadIdx.x;
    const v4i* s4 = (const v4i*)ei;
    const v4i* d4 = (const v4i*)(ei + E);
    int EQ = E >> 2;
    int q0 = blockIdx.x * (PART_TILE / 4);
    bool last = (blockIdx.x == gridDim.x - 1);
    v4i dsave[PT_ITERS];

    for (int j = t; j < NB_MAX; j += PART_THR) h[j] = 0;
    __syncthreads();
#pragma unroll
    for (int it = 0; it < PT_ITERS; ++it) {
        int q = q0 + it * PART_THR + t;
        v4i dd;
        if (q < EQ) {
            dd = __builtin_nontemporal_load(d4 + q);
            atomicAdd(&h[dd.x >> NPB_SHIFT], 1);
            atomicAdd(&h[dd.y >> NPB_SHIFT], 1);
            atomicAdd(&h[dd.z >> NPB_SHIFT], 1);
            atomicAdd(&h[dd.w >> NPB_SHIFT], 1);
            atomicAdd(&deg[dd.x], 1);
            atomicAdd(&deg[dd.y], 1);
            atomicAdd(&deg[dd.z], 1);
            atomicAdd(&deg[dd.w], 1);
        }
        dsave[it] = dd;
    }
    if (last) {
        for (int e = (EQ << 2) + t; e < E; e += PART_THR) {
            int d = ei[E + e];
            atomicAdd(&h[d >> NPB_SHIFT], 1);
            atomicAdd(&deg[d], 1);
        }
    }
    __syncthreads();
    for (int j = t; j < NB_MAX; j += PART_THR) {
        int c = h[j];
        rb[j] = c ? atomicAdd(&cur[j], c) : 0;
        h[j] = 0;
    }
    __syncthreads();
#pragma unroll
    for (int it = 0; it < PT_ITERS; ++it) {
        int q = q0 + it * PART_THR + t;
        if (q < EQ) {
            v4i ss = __builtin_nontemporal_load(s4 + q);
            v4i dd = dsave[it];
#pragma unroll
            for (int k = 0; k < 4; ++k) {
                int s = ss[k], d = dd[k];
                int b = d >> NPB_SHIFT;
                int pos = rb[b] + atomicAdd(&h[b], 1);
                pairs[pos] = (s << NPB_SHIFT) | (d & (NPB - 1));
            }
        }
    }
    if (last) {
        for (int e = (EQ << 2) + t; e < E; e += PART_THR) {
            int s = ei[e], d = ei[E + e];
            int b = d >> NPB_SHIFT;
            int pos = rb[b] + atomicAdd(&h[b], 1);
            pairs[pos] = (s << NPB_SHIFT) | (d & (NPB - 1));
        }
    }
}

// g1[n,:] = fp16( (x[n,:] @ W1) * dinv[n] ), dinv computed here from deg.
__global__ __launch_bounds__(256) void k_xform1(const float* __restrict__ x,
                                                const float* __restrict__ W1,
                                                const int* __restrict__ deg,
                                                float* __restrict__ dinv,
                                                __half* __restrict__ g, int N) {
    __shared__ float xs[16][132];
    __shared__ float ws[128 * 16];
    __shared__ float dvs[16];
    int t = threadIdx.x;
    int n0 = blockIdx.x * 16;
    const v4f* w4 = (const v4f*)W1;
    const v4f* x4 = (const v4f*)x;
    for (int idx = t; idx < 512; idx += 256) ((v4f*)ws)[idx] = w4[idx];
    for (int idx = t; idx < 512; idx += 256) {
        int r = idx >> 5, c4 = idx & 31;
        int n = n0 + r;
        v4f v = (n < N) ? x4[(size_t)n * 32 + c4] : (v4f)(0.f);
        *(v4f*)&xs[r][c4 * 4] = v;
    }
    if (t < 16) {
        int n = n0 + t;
        if (n < N) {
            float dv = rsqrtf((float)(deg[n] + 1));
            dinv[n] = dv;
            dvs[t] = dv;
        }
    }
    __syncthreads();
    int node = t >> 4, f = t & 15;
    int n = n0 + node;
    if (n < N) {
        float sum = 0.f;
#pragma unroll
        for (int k = 0; k < 128; ++k) sum += xs[node][k] * ws[k * 16 + f];
        g[(size_t)n * 16 + f] = __float2half_rn(sum * dvs[node]);
    }
}

// --- R9-proven edge-gather helpers: 2 lanes/edge, 16B dwordx4 gather ------
__device__ __forceinline__ v4i gather16(const __half* __restrict__ g, int p, int fo) {
    return *(const v4i*)(g + (size_t)(p >> NPB_SHIFT) * 16 + fo);
}
__device__ __forceinline__ void commit8(int* __restrict__ acc, int p, int fo, v4i r) {
    int* a = &acc[(p & (NPB - 1)) * 17 + fo];
#pragma unroll
    for (int j = 0; j < 4; ++j) {
        float2 f = __half22float2(((const __half2*)&r)[j]);
        atomicAdd(a + 2 * j,     __float2int_rn(f.x * FXSCALE));
        atomicAdd(a + 2 * j + 1, __float2int_rn(f.y * FXSCALE));
    }
}

// Layer-1: edge-parallel fixed-point aggregation + bucket-level W2 epilogue.
// g2[d,:] = fp16( relu(dinv*(sum+self)+b1) @ W2 * dinv )
// 512 thr = 8 waves; 128-node bucket; 4 blocks/CU -> all 782 blocks resident.
__global__ __launch_bounds__(512) void k_aggr1e(const __half* __restrict__ g1,
                                                const int* __restrict__ pairs,
                                                const int* __restrict__ cur,
                                                const float* __restrict__ dinv,
                                                const float* __restrict__ b1,
                                                const float* __restrict__ W2,
                                                __half* __restrict__ g2, int N) {
    __shared__ int   acc[NPB * 17];     // stride 17: spread banks; h1 later
    __shared__ float w2s[256];
    __shared__ float b1s[16];
    int t = threadIdx.x, b = blockIdx.x;
    int n0 = b << NPB_SHIFT;
    int base = b * BCAP;
    int cnt  = cur[b] - base;
    const int* pb = pairs + base;
    if (t < 256) w2s[t] = W2[t];
    if (t < 16)  b1s[t] = b1[t];
    for (int i = t; i < NPB * 17; i += 512) acc[i] = 0;
    __syncthreads();
    // 256 edge slots x 2 feature-halves; waves free-run (no stage, no sync)
    int es = t >> 1, fo = (t & 1) << 3;
    int e = es;
    for (; e + 768 < cnt; e += 1024) {
        int p0 = __builtin_nontemporal_load(pb + e);
        int p1 = __builtin_nontemporal_load(pb + e + 256);
        int p2 = __builtin_nontemporal_load(pb + e + 512);
        int p3 = __builtin_nontemporal_load(pb + e + 768);
        v4i r0 = gather16(g1, p0, fo);
        v4i r1 = gather16(g1, p1, fo);
        v4i r2 = gather16(g1, p2, fo);
        v4i r3 = gather16(g1, p3, fo);
        commit8(acc, p0, fo, r0);
        commit8(acc, p1, fo, r1);
        commit8(acc, p2, fo, r2);
        commit8(acc, p3, fo, r3);
    }
    for (; e < cnt; e += 256) {
        int p0 = pb[e];
        commit8(acc, p0, fo, gather16(g1, p0, fo));
    }
    __syncthreads();
    // phase A: acc -> h1 in place (each slot touched by exactly one thread)
#pragma unroll
    for (int r = 0; r < 4; ++r) {
        int idx = r * 512 + t;           // 2048 = 128*16
        int d = idx >> 4, f = idx & 15;
        int n = n0 + d;
        float hv = 0.f;
        if (n < N) {
            float sum  = (float)acc[d * 17 + f] * FXINV;
            float self = __half2float(g1[(size_t)n * 16 + f]);
            hv = fmaxf(dinv[n] * (sum + self) + b1s[f], 0.f);
        }
        acc[d * 17 + f] = __float_as_int(hv);
    }
    __syncthreads();
    // phase B: g2 = fp16((h1 @ W2) * dinv), 1024 half2 outputs
#pragma unroll
    for (int r = 0; r < 2; ++r) {
        int idx2 = r * 512 + t;          // 1024 = 128*8
        int d = idx2 >> 3, ff = idx2 & 7;
        int n = n0 + d;
        if (n < N) {
            float sx = 0.f, sy = 0.f;
#pragma unroll
            for (int k = 0; k < 16; ++k) {
                float hv = __int_as_float(acc[d * 17 + k]);
                sx += hv * w2s[k * 16 + 2 * ff];
                sy += hv * w2s[k * 16 + 2 * ff + 1];
            }
            float di = dinv[n];
            *(__half2*)(g2 + (size_t)n * 16 + 2 * ff) = __floats2half2_rn(sx * di, sy * di);
        }
    }
}

// Layer-2: edge-parallel fixed-point aggregation + bucket-level final GEMM.
// out[d,:] = relu(dinv*(sum+self)+b2) @ W_lin + b_lin
__global__ __launch_bounds__(512) void k_aggr2e(const __half* __restrict__ g2,
                                                const int* __restrict__ pairs,
                                                const int* __restrict__ cur,
                                                const float* __restrict__ dinv,
                                                const float* __restrict__ b2,
                                                const float* __restrict__ Wl,
                                                const float* __restrict__ bl,
                                                float* __restrict__ out, int N) {
    __shared__ int   acc[NPB * 17];
    __shared__ float wls[16 * 128];
    __shared__ float bls[128];
    __shared__ float b2s[16];
    int t = threadIdx.x, b = blockIdx.x;
    int n0 = b << NPB_SHIFT;
    int base = b * BCAP;
    int cnt  = cur[b] - base;
    const int* pb = pairs + base;
    ((v4f*)wls)[t] = ((const v4f*)Wl)[t];   // 512 v4f = 2048 floats exactly
    if (t < 128) bls[t] = bl[t];
    if (t < 16)  b2s[t] = b2[t];
    for (int i = t; i < NPB * 17; i += 512) acc[i] = 0;
    __syncthreads();
    int es = t >> 1, fo = (t & 1) << 3;
    int e = es;
    for (; e + 768 < cnt; e += 1024) {
        int p0 = __builtin_nontemporal_load(pb + e);
        int p1 = __builtin_nontemporal_load(pb + e + 256);
        int p2 = __builtin_nontemporal_load(pb + e + 512);
        int p3 = __builtin_nontemporal_load(pb + e + 768);
        v4i r0 = gather16(g2, p0, fo);
        v4i r1 = gather16(g2, p1, fo);
        v4i r2 = gather16(g2, p2, fo);
        v4i r3 = gather16(g2, p3, fo);
        commit8(acc, p0, fo, r0);
        commit8(acc, p1, fo, r1);
        commit8(acc, p2, fo, r2);
        commit8(acc, p3, fo, r3);
    }
    for (; e < cnt; e += 256) {
        int p0 = pb[e];
        commit8(acc, p0, fo, gather16(g2, p0, fo));
    }
    __syncthreads();
    // phase A: acc -> h2 in place
#pragma unroll
    for (int r = 0; r < 4; ++r) {
        int idx = r * 512 + t;
        int d = idx >> 4, f = idx & 15;
        int n = n0 + d;
        float hv = 0.f;
        if (n < N) {
            float sum  = (float)acc[d * 17 + f] * FXINV;
            float self = __half2float(g2[(size_t)n * 16 + f]);
            hv = fmaxf(dinv[n] * (sum + self) + b2s[f], 0.f);
        }
        acc[d * 17 + f] = __float_as_int(hv);
    }
    __syncthreads();
    // phase B: out = h2 @ W_lin + b_lin; 8192 float2 outputs, coalesced
    const v2f* wl2 = (const v2f*)wls;
#pragma unroll
    for (int r = 0; r < 16; ++r) {
        int idx2 = r * 512 + t;          // 8192 = 128*64
        int d = idx2 >> 6, fc = idx2 & 63;
        int n = n0 + d;
        if (n < N) {
            float ox = bls[2 * fc], oy = bls[2 * fc + 1];
#pragma unroll
            for (int k = 0; k < 16; ++k) {
                float hv = __int_as_float(acc[d * 17 + k]);
                v2f w = wl2[k * 64 + fc];
                ox += hv * w.x;
                oy += hv * w.y;
            }
            v2f o; o.x = ox; o.y = oy;
            __builtin_nontemporal_store(o, (v2f*)(out + (size_t)n * 128 + 2 * fc));
        }
    }
}

extern "C" void kernel_launch(void* const* d_in, const int* in_sizes, int n_in,
                              void* d_out, int out_size, void* d_ws, size_t ws_size,
                              hipStream_t stream) {
    const float* x  = (const float*)d_in[0];
    const int*   ei = (const int*)d_in[1];
    const float* W1 = (const float*)d_in[2];
    const float* b1 = (const float*)d_in[3];
    const float* W2 = (const float*)d_in[4];
    const float* b2 = (const float*)d_in[5];
    const float* Wl = (const float*)d_in[6];
    const float* bl = (const float*)d_in[7];
    float*       out = (float*)d_out;

    const int N = in_sizes[0] / 128;
    const int E = in_sizes[1] / 2;
    const int NB = (N + NPB - 1) >> NPB_SHIFT;   // buckets used (<= NB_MAX)

    char* ws = (char*)d_ws;
    auto carve = [&](size_t bytes) {
        char* p = ws;
        ws += (bytes + 255) & ~(size_t)255;
        return p;
    };
    int*    cur   = (int*)carve((size_t)NB_MAX * 4);
    int*    deg   = (int*)carve((size_t)N * 4);
    float*  dinv  = (float*)carve((size_t)N * 4);
    int*    pairs = (int*)carve((size_t)NB_MAX * BCAP * 4);
    __half* g1    = (__half*)carve((size_t)N * 16 * 2);
    __half* g2    = (__half*)carve((size_t)N * 16 * 2);
    (void)ws_size; (void)n_in; (void)out_size;

    hipMemsetAsync(deg, 0, (size_t)N * 4, stream);
    k_initcur<<<1, NB_MAX, 0, stream>>>(cur);
    k_partition<<<(E + PART_TILE - 1) / PART_TILE, PART_THR, 0, stream>>>(ei, cur, pairs, deg, E);
    k_xform1<<<(N + 15) / 16, 256, 0, stream>>>(x, W1, deg, dinv, g1, N);
    k_aggr1e<<<NB, 512, 0, stream>>>(g1, pairs, cur, dinv, b1, W2, g2, N);
    k_aggr2e<<<NB, 512, 0, stream>>>(g2, pairs, cur, dinv, b2, Wl, bl, out, N);
}

// Round 8
// 237.878 us; speedup vs baseline: 1.5115x; 1.5115x over previous
//
#include <hip/hip_runtime.h>
#include <hip/hip_fp16.h>

// ---------------------------------------------------------------------------
// GCN forward: h1 = relu(GCNConv(x, W1, b1)); h2 = relu(GCNConv(h1, W2, b2));
// out = h2 @ W_lin + b_lin
// N=100000, E=3200000, F_in=128, H=16, F_out=128.
// edge_index arrives as int32 [2*E]: row 0 = src, row 1 = dst.
//
// R16 pipeline (6 kernels): initcur -> partition -> deg -> xform1
//   -> aggr1e -> aggr2e.  Structure = R14 (best, 253.5us), with ONLY the
//   two counter-measured defects fixed:
//   (1) GRID BALANCE. R14 partition: 391 blocks/256 CUs -> occupancy 51%,
//       aggr: 391 blocks -> occupancy 43% (makespan = 2 ragged rounds).
//       R16: partition = exactly 512 blocks (2/CU, all resident, QT-range);
//       aggr: NPB 256->196 -> NB=511 buckets = 255 CUs x 2 + 1 (balanced
//       2-round makespan at 0.77x bucket size). Aggr inner loops unchanged
//       (1024 thr; R15's NPB=128/512-thr variant regressed -> reverted).
//       d/196 via exact magic multiply (d*87652394)>>34 (d < 2^17).
//   (2) NO PER-EDGE GLOBAL ATOMICS. R15's "fire-and-forget" deg atomics:
//       device-scope RMW past non-coherent XCD L2s = 120MB fabric writes,
//       partition 152us @ VALUBusy 0.8%. (Same mechanism as R13's scatter.)
//       deg stays in k_deg as per-bucket LDS hist over pairs (R14-proven).
// Fixed-point scale 2^18: quantization 3.8e-6/edge << fp16 4.9e-4; int sums
// exact & order-independent (deterministic). Overflow margin ~19x.
// ---------------------------------------------------------------------------

typedef int   v4i __attribute__((ext_vector_type(4)));
typedef float v4f __attribute__((ext_vector_type(4)));
typedef float v2f __attribute__((ext_vector_type(2)));

#define NPB        196    // nodes per bucket -> NB=511 = balanced on 256 CUs
#define NB_MAX     512    // max buckets
#define BCAP       8192   // per-bucket pairs capacity (mean 6272, sigma~79, +24s)
#define PACK_SHIFT 8      // pairs = (src << 8) | dstlocal  (dstlocal < 196)
#define PACK_MASK  255
#define PART_GRID  512    // partition blocks: exactly 2 per CU
#define FXSCALE    262144.0f          // 2^18
#define FXINV      (1.0f / 262144.0f)

// exact floor(d/196) for 0 <= d < 2^17  (magic: ceil(2^34/196) = 87652394)
__device__ __forceinline__ int bucket_of(int d) {
    return (int)(((unsigned long long)(unsigned)d * 87652394ull) >> 34);
}

// cur[b] = b*BCAP  (fixed bucket bases; no counting pass needed)
__global__ __launch_bounds__(NB_MAX) void k_initcur(int* __restrict__ cur) {
    cur[threadIdx.x] = threadIdx.x * BCAP;
}

// Partition edges into bucket-contiguous packed (src<<8 | dstlocal) runs.
// Per-block LDS hist -> ONE global atomic per (block,bucket) reserving a
// dense run (R13/R15 lesson: never per-edge global atomics). 512 blocks,
// contiguous quad ranges, all blocks resident -> no dispatch tail.
__global__ __launch_bounds__(1024) void k_partition(const int* __restrict__ ei,
                                                    int* __restrict__ cur,
                                                    int* __restrict__ pairs,
                                                    int E, int QT) {
    __shared__ int h[NB_MAX];    // pass1: local hist; pass2: local cursor
    __shared__ int rb[NB_MAX];   // run base (absolute) per bucket
    int t = threadIdx.x;
    const v4i* s4 = (const v4i*)ei;
    const v4i* d4 = (const v4i*)(ei + E);
    int EQ = E >> 2;
    int Q0 = blockIdx.x * QT;
    int Q1 = min(Q0 + QT, EQ);
    bool last = (blockIdx.x == gridDim.x - 1);

    for (int j = t; j < NB_MAX; j += 1024) h[j] = 0;
    __syncthreads();
    for (int q = Q0 + t; q < Q1; q += 1024) {
        v4i dd = __builtin_nontemporal_load(d4 + q);
        atomicAdd(&h[bucket_of(dd.x)], 1);
        atomicAdd(&h[bucket_of(dd.y)], 1);
        atomicAdd(&h[bucket_of(dd.z)], 1);
        atomicAdd(&h[bucket_of(dd.w)], 1);
    }
    if (last) {
        for (int e = (EQ << 2) + t; e < E; e += 1024)
            atomicAdd(&h[bucket_of(ei[E + e])], 1);
    }
    __syncthreads();
    for (int j = t; j < NB_MAX; j += 1024) {
        int c = h[j];
        rb[j] = c ? atomicAdd(&cur[j], c) : 0;
        h[j] = 0;
    }
    __syncthreads();
    for (int q = Q0 + t; q < Q1; q += 1024) {
        v4i ss = __builtin_nontemporal_load(s4 + q);
        v4i dd = __builtin_nontemporal_load(d4 + q);
#pragma unroll
        for (int k = 0; k < 4; ++k) {
            int s = ss[k], d = dd[k];
            int b = bucket_of(d);
            int pos = rb[b] + atomicAdd(&h[b], 1);
            pairs[pos] = (s << PACK_SHIFT) | (d - b * NPB);
        }
    }
    if (last) {
        for (int e = (EQ << 2) + t; e < E; e += 1024) {
            int s = ei[e], d = ei[E + e];
            int b = bucket_of(d);
            int pos = rb[b] + atomicAdd(&h[b], 1);
            pairs[pos] = (s << PACK_SHIFT) | (d - b * NPB);
        }
    }
}

// One block per bucket: int LDS deg hist -> dinv (deg+1 self-loop).
// cnt = cur[b] - b*BCAP (cursor past-the-end after partition).
__global__ __launch_bounds__(256) void k_deg(const int* __restrict__ pairs,
                                             const int* __restrict__ cur,
                                             float* __restrict__ dinv, int N) {
    __shared__ int deg[NPB];
    int b = blockIdx.x, t = threadIdx.x;
    int base = b * BCAP;
    int cnt  = cur[b] - base;
    if (t < NPB) deg[t] = 0;
    __syncthreads();
    const v4i* p4 = (const v4i*)(pairs + base);
    int cq = cnt >> 2;
    for (int q = t; q < cq; q += 256) {
        v4i pp = __builtin_nontemporal_load(p4 + q);
        atomicAdd(&deg[pp.x & PACK_MASK], 1);
        atomicAdd(&deg[pp.y & PACK_MASK], 1);
        atomicAdd(&deg[pp.z & PACK_MASK], 1);
        atomicAdd(&deg[pp.w & PACK_MASK], 1);
    }
    for (int i = (cq << 2) + t; i < cnt; i += 256)
        atomicAdd(&deg[pairs[base + i] & PACK_MASK], 1);
    __syncthreads();
    int n = b * NPB + t;
    if (t < NPB && n < N) dinv[n] = rsqrtf((float)(deg[t] + 1));
}

// g1[n,:] = fp16( (x[n,:] @ W1) * dinv[n] )   (128 -> 16), 16 nodes per block
__global__ __launch_bounds__(256) void k_xform1(const float* __restrict__ x,
                                                const float* __restrict__ W1,
                                                const float* __restrict__ dinv,
                                                __half* __restrict__ g, int N) {
    __shared__ float xs[16][132];
    __shared__ float ws[128 * 16];
    int t = threadIdx.x;
    int n0 = blockIdx.x * 16;
    const v4f* w4 = (const v4f*)W1;
    const v4f* x4 = (const v4f*)x;
    for (int idx = t; idx < 512; idx += 256) ((v4f*)ws)[idx] = w4[idx];
    for (int idx = t; idx < 512; idx += 256) {
        int r = idx >> 5, c4 = idx & 31;
        int n = n0 + r;
        v4f v = (n < N) ? x4[(size_t)n * 32 + c4] : (v4f)(0.f);
        *(v4f*)&xs[r][c4 * 4] = v;
    }
    __syncthreads();
    int node = t >> 4, f = t & 15;
    int n = n0 + node;
    if (n < N) {
        float sum = 0.f;
#pragma unroll
        for (int k = 0; k < 128; ++k) sum += xs[node][k] * ws[k * 16 + f];
        g[(size_t)n * 16 + f] = __float2half_rn(sum * dinv[n]);
    }
}

// --- edge-gather helpers: 2 lanes/edge, 16B dwordx4 gather (R9-proven) ----
__device__ __forceinline__ v4i gather16(const __half* __restrict__ g, int p, int fo) {
    return *(const v4i*)(g + (size_t)(p >> PACK_SHIFT) * 16 + fo);
}
__device__ __forceinline__ void commit8(int* __restrict__ acc, int p, int fo, v4i r) {
    int* a = &acc[(p & PACK_MASK) * 17 + fo];
#pragma unroll
    for (int j = 0; j < 4; ++j) {
        float2 f = __half22float2(((const __half2*)&r)[j]);
        atomicAdd(a + 2 * j,     __float2int_rn(f.x * FXSCALE));
        atomicAdd(a + 2 * j + 1, __float2int_rn(f.y * FXSCALE));
    }
}

// Layer-1: edge-parallel fixed-point aggregation + bucket-level W2 epilogue.
// g2[d,:] = fp16( relu(dinv*(sum+self)+b1) @ W2 * dinv )
__global__ __launch_bounds__(1024) void k_aggr1e(const __half* __restrict__ g1,
                                                 const int* __restrict__ pairs,
                                                 const int* __restrict__ cur,
                                                 const float* __restrict__ dinv,
                                                 const float* __restrict__ b1,
                                                 const float* __restrict__ W2,
                                                 __half* __restrict__ g2, int N) {
    __shared__ int   acc[NPB * 17];     // stride 17: spread banks; h1 later
    __shared__ float w2s[256];
    __shared__ float b1s[16];
    int t = threadIdx.x, b = blockIdx.x;
    int n0 = b * NPB;
    int base = b * BCAP;
    int cnt  = cur[b] - base;
    const int* pb = pairs + base;
    if (t < 256) w2s[t] = W2[t];
    if (t < 16)  b1s[t] = b1[t];
    for (int i = t; i < NPB * 17; i += 1024) acc[i] = 0;
    __syncthreads();
    // 512 edge slots x 2 feature-halves; waves free-run (no stage, no sync)
    int es = t >> 1, fo = (t & 1) << 3;
    int e = es;
    for (; e + 1536 < cnt; e += 2048) {
        int p0 = __builtin_nontemporal_load(pb + e);
        int p1 = __builtin_nontemporal_load(pb + e + 512);
        int p2 = __builtin_nontemporal_load(pb + e + 1024);
        int p3 = __builtin_nontemporal_load(pb + e + 1536);
        v4i r0 = gather16(g1, p0, fo);
        v4i r1 = gather16(g1, p1, fo);
        v4i r2 = gather16(g1, p2, fo);
        v4i r3 = gather16(g1, p3, fo);
        commit8(acc, p0, fo, r0);
        commit8(acc, p1, fo, r1);
        commit8(acc, p2, fo, r2);
        commit8(acc, p3, fo, r3);
    }
    for (; e < cnt; e += 512) {
        int p0 = pb[e];
        commit8(acc, p0, fo, gather16(g1, p0, fo));
    }
    __syncthreads();
    // phase A: acc -> h1 in place (each slot touched by exactly one thread)
#pragma unroll
    for (int r = 0; r < 4; ++r) {
        int idx = r * 1024 + t;          // NPB*16 = 3136 slots
        if (idx < NPB * 16) {
            int d = idx >> 4, f = idx & 15;
            int n = n0 + d;
            float hv = 0.f;
            if (n < N) {
                float sum  = (float)acc[d * 17 + f] * FXINV;
                float self = __half2float(g1[(size_t)n * 16 + f]);
                hv = fmaxf(dinv[n] * (sum + self) + b1s[f], 0.f);
            }
            acc[d * 17 + f] = __float_as_int(hv);
        }
    }
    __syncthreads();
    // phase B: g2 = fp16((h1 @ W2) * dinv), NPB*8 = 1568 half2 outputs
#pragma unroll
    for (int r = 0; r < 2; ++r) {
        int idx2 = r * 1024 + t;
        if (idx2 < NPB * 8) {
            int d = idx2 >> 3, ff = idx2 & 7;
            int n = n0 + d;
            if (n < N) {
                float sx = 0.f, sy = 0.f;
#pragma unroll
                for (int k = 0; k < 16; ++k) {
                    float hv = __int_as_float(acc[d * 17 + k]);
                    sx += hv * w2s[k * 16 + 2 * ff];
                    sy += hv * w2s[k * 16 + 2 * ff + 1];
                }
                float di = dinv[n];
                *(__half2*)(g2 + (size_t)n * 16 + 2 * ff) = __floats2half2_rn(sx * di, sy * di);
            }
        }
    }
}

// Layer-2: edge-parallel fixed-point aggregation + bucket-level final GEMM.
// out[d,:] = relu(dinv*(sum+self)+b2) @ W_lin + b_lin
__global__ __launch_bounds__(1024) void k_aggr2e(const __half* __restrict__ g2,
                                                 const int* __restrict__ pairs,
                                                 const int* __restrict__ cur,
                                                 const float* __restrict__ dinv,
                                                 const float* __restrict__ b2,
                                                 const float* __restrict__ Wl,
                                                 const float* __restrict__ bl,
                                                 float* __restrict__ out, int N) {
    __shared__ int   acc[NPB * 17];
    __shared__ float wls[16 * 128];
    __shared__ float bls[128];
    __shared__ float b2s[16];
    int t = threadIdx.x, b = blockIdx.x;
    int n0 = b * NPB;
    int base = b * BCAP;
    int cnt  = cur[b] - base;
    const int* pb = pairs + base;
    if (t < 512) ((v4f*)wls)[t] = ((const v4f*)Wl)[t];
    if (t < 128) bls[t] = bl[t];
    if (t < 16)  b2s[t] = b2[t];
    for (int i = t; i < NPB * 17; i += 1024) acc[i] = 0;
    __syncthreads();
    int es = t >> 1, fo = (t & 1) << 3;
    int e = es;
    for (; e + 1536 < cnt; e += 2048) {
        int p0 = __builtin_nontemporal_load(pb + e);
        int p1 = __builtin_nontemporal_load(pb + e + 512);
        int p2 = __builtin_nontemporal_load(pb + e + 1024);
        int p3 = __builtin_nontemporal_load(pb + e + 1536);
        v4i r0 = gather16(g2, p0, fo);
        v4i r1 = gather16(g2, p1, fo);
        v4i r2 = gather16(g2, p2, fo);
        v4i r3 = gather16(g2, p3, fo);
        commit8(acc, p0, fo, r0);
        commit8(acc, p1, fo, r1);
        commit8(acc, p2, fo, r2);
        commit8(acc, p3, fo, r3);
    }
    for (; e < cnt; e += 512) {
        int p0 = pb[e];
        commit8(acc, p0, fo, gather16(g2, p0, fo));
    }
    __syncthreads();
    // phase A: acc -> h2 in place
#pragma unroll
    for (int r = 0; r < 4; ++r) {
        int idx = r * 1024 + t;          // NPB*16 = 3136 slots
        if (idx < NPB * 16) {
            int d = idx >> 4, f = idx & 15;
            int n = n0 + d;
            float hv = 0.f;
            if (n < N) {
                float sum  = (float)acc[d * 17 + f] * FXINV;
                float self = __half2float(g2[(size_t)n * 16 + f]);
                hv = fmaxf(dinv[n] * (sum + self) + b2s[f], 0.f);
            }
            acc[d * 17 + f] = __float_as_int(hv);
        }
    }
    __syncthreads();
    // phase B: out = h2 @ W_lin + b_lin; NPB*64 = 12544 float2, coalesced
    const v2f* wl2 = (const v2f*)wls;
#pragma unroll
    for (int r = 0; r < 13; ++r) {
        int idx2 = r * 1024 + t;
        if (idx2 < NPB * 64) {
            int d = idx2 >> 6, fc = idx2 & 63;
            int n = n0 + d;
            if (n < N) {
                float ox = bls[2 * fc], oy = bls[2 * fc + 1];
#pragma unroll
                for (int k = 0; k < 16; ++k) {
                    float hv = __int_as_float(acc[d * 17 + k]);
                    v2f w = wl2[k * 64 + fc];
                    ox += hv * w.x;
                    oy += hv * w.y;
                }
                v2f o; o.x = ox; o.y = oy;
                __builtin_nontemporal_store(o, (v2f*)(out + (size_t)n * 128 + 2 * fc));
            }
        }
    }
}

extern "C" void kernel_launch(void* const* d_in, const int* in_sizes, int n_in,
                              void* d_out, int out_size, void* d_ws, size_t ws_size,
                              hipStream_t stream) {
    const float* x  = (const float*)d_in[0];
    const int*   ei = (const int*)d_in[1];
    const float* W1 = (const float*)d_in[2];
    const float* b1 = (const float*)d_in[3];
    const float* W2 = (const float*)d_in[4];
    const float* b2 = (const float*)d_in[5];
    const float* Wl = (const float*)d_in[6];
    const float* bl = (const float*)d_in[7];
    float*       out = (float*)d_out;

    const int N = in_sizes[0] / 128;
    const int E = in_sizes[1] / 2;
    const int NB = (N + NPB - 1) / NPB;          // buckets used (<= NB_MAX)
    const int EQ = E >> 2;
    const int QT = (EQ + PART_GRID - 1) / PART_GRID;

    char* ws = (char*)d_ws;
    auto carve = [&](size_t bytes) {
        char* p = ws;
        ws += (bytes + 255) & ~(size_t)255;
        return p;
    };
    int*    cur   = (int*)carve((size_t)NB_MAX * 4);
    float*  dinv  = (float*)carve((size_t)N * 4);
    int*    pairs = (int*)carve((size_t)NB_MAX * BCAP * 4);
    __half* g1    = (__half*)carve((size_t)N * 16 * 2);
    __half* g2    = (__half*)carve((size_t)N * 16 * 2);
    (void)ws_size; (void)n_in; (void)out_size;

    k_initcur<<<1, NB_MAX, 0, stream>>>(cur);
    k_partition<<<PART_GRID, 1024, 0, stream>>>(ei, cur, pairs, E, QT);
    k_deg<<<NB, 256, 0, stream>>>(pairs, cur, dinv, N);
    k_xform1<<<(N + 15) / 16, 256, 0, stream>>>(x, W1, dinv, g1, N);
    k_aggr1e<<<NB, 1024, 0, stream>>>(g1, pairs, cur, dinv, b1, W2, g2, N);
    k_aggr2e<<<NB, 1024, 0, stream>>>(g2, pairs, cur, dinv, b2, Wl, bl, out, N);
}

// Round 9
// 232.745 us; speedup vs baseline: 1.5449x; 1.0221x over previous
//
#include <hip/hip_runtime.h>
#include <hip/hip_fp16.h>

// ---------------------------------------------------------------------------
// GCN forward: h1 = relu(GCNConv(x, W1, b1)); h2 = relu(GCNConv(h1, W2, b2));
// out = h2 @ W_lin + b_lin
// N=100000, E=3200000, F_in=128, H=16, F_out=128.
// edge_index arrives as int32 [2*E]: row 0 = src, row 1 = dst.
//
// R17 pipeline (6 kernels): initcur -> partition -> deg -> xform1
//   -> aggr1e -> aggr2e.  Structure = R16 (best, 237.9us). Three
//   arithmetic-derived micro-fixes, no structural change:
//   (1) k_deg 256 -> 1024 threads: it re-reads 25.6MB of pairs latency-
//       bound at only ~8 waves/CU; 1024 thr -> 32 waves/CU (same fix that
//       took aggr 55->45.5 in R16).
//   (2) k_xform1 was LDS-ISSUE-bound: 256 scalar ds_read_b32 per output
//       (ws[k*16+f] is stride-16). Stage W1 TRANSPOSED (wsT[f][k], row pad
//       132 -> rows 16B-aligned) so both operands use ds_read_b128:
//       64 LDS instrs per output instead of 256.
//   (3) aggr pairs reads: one dwordx4 of 4 consecutive pairs per lane-pair
//       instead of 4 scalar loads (BCAP over-allocation makes the aligned
//       16B load safe; commits guarded to < cnt).
// R13/R15 standing rule: NEVER per-edge global atomics (fabric RMW death).
// R16 standing rule: grids sized/balanced to CU count (partition 512 blocks,
// aggr 511 buckets of 196 = 255 CUs x 2 + 1).
// Fixed-point scale 2^18: quantization 3.8e-6/edge << fp16 4.9e-4; int sums
// exact & order-independent (deterministic). Overflow margin ~19x.
// ---------------------------------------------------------------------------

typedef int   v4i __attribute__((ext_vector_type(4)));
typedef float v4f __attribute__((ext_vector_type(4)));
typedef float v2f __attribute__((ext_vector_type(2)));

#define NPB        196    // nodes per bucket -> NB=511 = balanced on 256 CUs
#define NB_MAX     512    // max buckets
#define BCAP       8192   // per-bucket pairs capacity (mean 6272, sigma~79, +24s)
#define PACK_SHIFT 8      // pairs = (src << 8) | dstlocal  (dstlocal < 196)
#define PACK_MASK  255
#define PART_GRID  512    // partition blocks: exactly 2 per CU
#define FXSCALE    262144.0f          // 2^18
#define FXINV      (1.0f / 262144.0f)

// exact floor(d/196) for 0 <= d < 2^17  (magic: ceil(2^34/196) = 87652394)
__device__ __forceinline__ int bucket_of(int d) {
    return (int)(((unsigned long long)(unsigned)d * 87652394ull) >> 34);
}

// cur[b] = b*BCAP  (fixed bucket bases; no counting pass needed)
__global__ __launch_bounds__(NB_MAX) void k_initcur(int* __restrict__ cur) {
    cur[threadIdx.x] = threadIdx.x * BCAP;
}

// Partition edges into bucket-contiguous packed (src<<8 | dstlocal) runs.
// Per-block LDS hist -> ONE global atomic per (block,bucket) reserving a
// dense run. 512 blocks, contiguous quad ranges, all resident.
__global__ __launch_bounds__(1024) void k_partition(const int* __restrict__ ei,
                                                    int* __restrict__ cur,
                                                    int* __restrict__ pairs,
                                                    int E, int QT) {
    __shared__ int h[NB_MAX];    // pass1: local hist; pass2: local cursor
    __shared__ int rb[NB_MAX];   // run base (absolute) per bucket
    int t = threadIdx.x;
    const v4i* s4 = (const v4i*)ei;
    const v4i* d4 = (const v4i*)(ei + E);
    int EQ = E >> 2;
    int Q0 = blockIdx.x * QT;
    int Q1 = min(Q0 + QT, EQ);
    bool last = (blockIdx.x == gridDim.x - 1);

    for (int j = t; j < NB_MAX; j += 1024) h[j] = 0;
    __syncthreads();
    for (int q = Q0 + t; q < Q1; q += 1024) {
        v4i dd = __builtin_nontemporal_load(d4 + q);
        atomicAdd(&h[bucket_of(dd.x)], 1);
        atomicAdd(&h[bucket_of(dd.y)], 1);
        atomicAdd(&h[bucket_of(dd.z)], 1);
        atomicAdd(&h[bucket_of(dd.w)], 1);
    }
    if (last) {
        for (int e = (EQ << 2) + t; e < E; e += 1024)
            atomicAdd(&h[bucket_of(ei[E + e])], 1);
    }
    __syncthreads();
    for (int j = t; j < NB_MAX; j += 1024) {
        int c = h[j];
        rb[j] = c ? atomicAdd(&cur[j], c) : 0;
        h[j] = 0;
    }
    __syncthreads();
    for (int q = Q0 + t; q < Q1; q += 1024) {
        v4i ss = __builtin_nontemporal_load(s4 + q);
        v4i dd = __builtin_nontemporal_load(d4 + q);
#pragma unroll
        for (int k = 0; k < 4; ++k) {
            int s = ss[k], d = dd[k];
            int b = bucket_of(d);
            int pos = rb[b] + atomicAdd(&h[b], 1);
            pairs[pos] = (s << PACK_SHIFT) | (d - b * NPB);
        }
    }
    if (last) {
        for (int e = (EQ << 2) + t; e < E; e += 1024) {
            int s = ei[e], d = ei[E + e];
            int b = bucket_of(d);
            int pos = rb[b] + atomicAdd(&h[b], 1);
            pairs[pos] = (s << PACK_SHIFT) | (d - b * NPB);
        }
    }
}

// One block per bucket: int LDS deg hist -> dinv (deg+1 self-loop).
// R17: 1024 threads (was 256) -> 32 waves/CU to hide the L2 read latency.
__global__ __launch_bounds__(1024) void k_deg(const int* __restrict__ pairs,
                                              const int* __restrict__ cur,
                                              float* __restrict__ dinv, int N) {
    __shared__ int deg[NPB];
    int b = blockIdx.x, t = threadIdx.x;
    int base = b * BCAP;
    int cnt  = cur[b] - base;
    if (t < NPB) deg[t] = 0;
    __syncthreads();
    const v4i* p4 = (const v4i*)(pairs + base);
    int cq = cnt >> 2;
    for (int q = t; q < cq; q += 1024) {
        v4i pp = __builtin_nontemporal_load(p4 + q);
        atomicAdd(&deg[pp.x & PACK_MASK], 1);
        atomicAdd(&deg[pp.y & PACK_MASK], 1);
        atomicAdd(&deg[pp.z & PACK_MASK], 1);
        atomicAdd(&deg[pp.w & PACK_MASK], 1);
    }
    for (int i = (cq << 2) + t; i < cnt; i += 1024)
        atomicAdd(&deg[pairs[base + i] & PACK_MASK], 1);
    __syncthreads();
    int n = b * NPB + t;
    if (t < NPB && n < N) dinv[n] = rsqrtf((float)(deg[t] + 1));
}

// g1[n,:] = fp16( (x[n,:] @ W1) * dinv[n] )   (128 -> 16), 16 nodes per block
// R17: W1 staged TRANSPOSED -> inner loop is b128 x b128 LDS reads (4x fewer
// LDS instructions; was stride-16 scalar ds_read on ws).
__global__ __launch_bounds__(256) void k_xform1(const float* __restrict__ x,
                                                const float* __restrict__ W1,
                                                const float* __restrict__ dinv,
                                                __half* __restrict__ g, int N) {
    __shared__ float xs[16][132];    // row = 528B, 16B-aligned
    __shared__ float wsT[16][132];   // wsT[f][k] = W1[k*16+f]
    int t = threadIdx.x;
    int n0 = blockIdx.x * 16;
    const v4f* x4 = (const v4f*)x;
    for (int idx = t; idx < 2048; idx += 256) {
        int k = idx >> 4, f = idx & 15;
        wsT[f][k] = W1[idx];         // coalesced read; 2-way LDS bank alias (free)
    }
    for (int idx = t; idx < 512; idx += 256) {
        int r = idx >> 5, c4 = idx & 31;
        int n = n0 + r;
        v4f v = (n < N) ? x4[(size_t)n * 32 + c4] : (v4f)(0.f);
        *(v4f*)&xs[r][c4 * 4] = v;
    }
    __syncthreads();
    int node = t >> 4, f = t & 15;
    int n = n0 + node;
    if (n < N) {
        const v4f* xr = (const v4f*)&xs[node][0];
        const v4f* wr = (const v4f*)&wsT[f][0];
        float sum = 0.f;
#pragma unroll
        for (int k4 = 0; k4 < 32; ++k4) {
            v4f a = xr[k4], w = wr[k4];
            sum += a.x * w.x + a.y * w.y + a.z * w.z + a.w * w.w;
        }
        g[(size_t)n * 16 + f] = __float2half_rn(sum * dinv[n]);
    }
}

// --- edge-gather helpers: 2 lanes/edge, 16B dwordx4 gather (R9-proven) ----
__device__ __forceinline__ v4i gather16(const __half* __restrict__ g, int p, int fo) {
    return *(const v4i*)(g + (size_t)(p >> PACK_SHIFT) * 16 + fo);
}
__device__ __forceinline__ void commit8(int* __restrict__ acc, int p, int fo, v4i r) {
    int* a = &acc[(p & PACK_MASK) * 17 + fo];
#pragma unroll
    for (int j = 0; j < 4; ++j) {
        float2 f = __half22float2(((const __half2*)&r)[j]);
        atomicAdd(a + 2 * j,     __float2int_rn(f.x * FXSCALE));
        atomicAdd(a + 2 * j + 1, __float2int_rn(f.y * FXSCALE));
    }
}

// Layer-1: edge-parallel fixed-point aggregation + bucket-level W2 epilogue.
// g2[d,:] = fp16( relu(dinv*(sum+self)+b1) @ W2 * dinv )
__global__ __launch_bounds__(1024) void k_aggr1e(const __half* __restrict__ g1,
                                                 const int* __restrict__ pairs,
                                                 const int* __restrict__ cur,
                                                 const float* __restrict__ dinv,
                                                 const float* __restrict__ b1,
                                                 const float* __restrict__ W2,
                                                 __half* __restrict__ g2, int N) {
    __shared__ int   acc[NPB * 17];     // stride 17: spread banks; h1 later
    __shared__ float w2s[256];
    __shared__ float b1s[16];
    int t = threadIdx.x, b = blockIdx.x;
    int n0 = b * NPB;
    int base = b * BCAP;
    int cnt  = cur[b] - base;
    const int* pb = pairs + base;
    if (t < 256) w2s[t] = W2[t];
    if (t < 16)  b1s[t] = b1[t];
    for (int i = t; i < NPB * 17; i += 1024) acc[i] = 0;
    __syncthreads();
    // lane-pair handles 4 consecutive edges via one dwordx4 pairs load;
    // 512 lane-pairs x 4 = 2048 edges per sweep; waves free-run.
    int fo = (t & 1) << 3;
    int ep = (t >> 1) << 2;
    int cnt4 = cnt & ~3;
    for (int e = ep; e + 4 <= cnt4; e += 2048) {
        v4i pp = __builtin_nontemporal_load((const v4i*)(pb + e));
        v4i r0 = gather16(g1, pp.x, fo);
        v4i r1 = gather16(g1, pp.y, fo);
        v4i r2 = gather16(g1, pp.z, fo);
        v4i r3 = gather16(g1, pp.w, fo);
        commit8(acc, pp.x, fo, r0);
        commit8(acc, pp.y, fo, r1);
        commit8(acc, pp.z, fo, r2);
        commit8(acc, pp.w, fo, r3);
    }
    for (int i = cnt4 + (t >> 1); i < cnt; i += 512) {
        int p0 = pb[i];
        commit8(acc, p0, fo, gather16(g1, p0, fo));
    }
    __syncthreads();
    // phase A: acc -> h1 in place (each slot touched by exactly one thread)
#pragma unroll
    for (int r = 0; r < 4; ++r) {
        int idx = r * 1024 + t;          // NPB*16 = 3136 slots
        if (idx < NPB * 16) {
            int d = idx >> 4, f = idx & 15;
            int n = n0 + d;
            float hv = 0.f;
            if (n < N) {
                float sum  = (float)acc[d * 17 + f] * FXINV;
                float self = __half2float(g1[(size_t)n * 16 + f]);
                hv = fmaxf(dinv[n] * (sum + self) + b1s[f], 0.f);
            }
            acc[d * 17 + f] = __float_as_int(hv);
        }
    }
    __syncthreads();
    // phase B: g2 = fp16((h1 @ W2) * dinv), NPB*8 = 1568 half2 outputs
#pragma unroll
    for (int r = 0; r < 2; ++r) {
        int idx2 = r * 1024 + t;
        if (idx2 < NPB * 8) {
            int d = idx2 >> 3, ff = idx2 & 7;
            int n = n0 + d;
            if (n < N) {
                float sx = 0.f, sy = 0.f;
#pragma unroll
                for (int k = 0; k < 16; ++k) {
                    float hv = __int_as_float(acc[d * 17 + k]);
                    sx += hv * w2s[k * 16 + 2 * ff];
                    sy += hv * w2s[k * 16 + 2 * ff + 1];
                }
                float di = dinv[n];
                *(__half2*)(g2 + (size_t)n * 16 + 2 * ff) = __floats2half2_rn(sx * di, sy * di);
            }
        }
    }
}

// Layer-2: edge-parallel fixed-point aggregation + bucket-level final GEMM.
// out[d,:] = relu(dinv*(sum+self)+b2) @ W_lin + b_lin
__global__ __launch_bounds__(1024) void k_aggr2e(const __half* __restrict__ g2,
                                                 const int* __restrict__ pairs,
                                                 const int* __restrict__ cur,
                                                 const float* __restrict__ dinv,
                                                 const float* __restrict__ b2,
                                                 const float* __restrict__ Wl,
                                                 const float* __restrict__ bl,
                                                 float* __restrict__ out, int N) {
    __shared__ int   acc[NPB * 17];
    __shared__ float wls[16 * 128];
    __shared__ float bls[128];
    __shared__ float b2s[16];
    int t = threadIdx.x, b = blockIdx.x;
    int n0 = b * NPB;
    int base = b * BCAP;
    int cnt  = cur[b] - base;
    const int* pb = pairs + base;
    if (t < 512) ((v4f*)wls)[t] = ((const v4f*)Wl)[t];
    if (t < 128) bls[t] = bl[t];
    if (t < 16)  b2s[t] = b2[t];
    for (int i = t; i < NPB * 17; i += 1024) acc[i] = 0;
    __syncthreads();
    int fo = (t & 1) << 3;
    int ep = (t >> 1) << 2;
    int cnt4 = cnt & ~3;
    for (int e = ep; e + 4 <= cnt4; e += 2048) {
        v4i pp = __builtin_nontemporal_load((const v4i*)(pb + e));
        v4i r0 = gather16(g2, pp.x, fo);
        v4i r1 = gather16(g2, pp.y, fo);
        v4i r2 = gather16(g2, pp.z, fo);
        v4i r3 = gather16(g2, pp.w, fo);
        commit8(acc, pp.x, fo, r0);
        commit8(acc, pp.y, fo, r1);
        commit8(acc, pp.z, fo, r2);
        commit8(acc, pp.w, fo, r3);
    }
    for (int i = cnt4 + (t >> 1); i < cnt; i += 512) {
        int p0 = pb[i];
        commit8(acc, p0, fo, gather16(g2, p0, fo));
    }
    __syncthreads();
    // phase A: acc -> h2 in place
#pragma unroll
    for (int r = 0; r < 4; ++r) {
        int idx = r * 1024 + t;          // NPB*16 = 3136 slots
        if (idx < NPB * 16) {
            int d = idx >> 4, f = idx & 15;
            int n = n0 + d;
            float hv = 0.f;
            if (n < N) {
                float sum  = (float)acc[d * 17 + f] * FXINV;
                float self = __half2float(g2[(size_t)n * 16 + f]);
                hv = fmaxf(dinv[n] * (sum + self) + b2s[f], 0.f);
            }
            acc[d * 17 + f] = __float_as_int(hv);
        }
    }
    __syncthreads();
    // phase B: out = h2 @ W_lin + b_lin; NPB*64 = 12544 float2, coalesced
    const v2f* wl2 = (const v2f*)wls;
#pragma unroll
    for (int r = 0; r < 13; ++r) {
        int idx2 = r * 1024 + t;
        if (idx2 < NPB * 64) {
            int d = idx2 >> 6, fc = idx2 & 63;
            int n = n0 + d;
            if (n < N) {
                float ox = bls[2 * fc], oy = bls[2 * fc + 1];
#pragma unroll
                for (int k = 0; k < 16; ++k) {
                    float hv = __int_as_float(acc[d * 17 + k]);
                    v2f w = wl2[k * 64 + fc];
                    ox += hv * w.x;
                    oy += hv * w.y;
                }
                v2f o; o.x = ox; o.y = oy;
                __builtin_nontemporal_store(o, (v2f*)(out + (size_t)n * 128 + 2 * fc));
            }
        }
    }
}

extern "C" void kernel_launch(void* const* d_in, const int* in_sizes, int n_in,
                              void* d_out, int out_size, void* d_ws, size_t ws_size,
                              hipStream_t stream) {
    const float* x  = (const float*)d_in[0];
    const int*   ei = (const int*)d_in[1];
    const float* W1 = (const float*)d_in[2];
    const float* b1 = (const float*)d_in[3];
    const float* W2 = (const float*)d_in[4];
    const float* b2 = (const float*)d_in[5];
    const float* Wl = (const float*)d_in[6];
    const float* bl = (const float*)d_in[7];
    float*       out = (float*)d_out;

    const int N = in_sizes[0] / 128;
    const int E = in_sizes[1] / 2;
    const int NB = (N + NPB - 1) / NPB;          // buckets used (<= NB_MAX)
    const int EQ = E >> 2;
    const int QT = (EQ + PART_GRID - 1) / PART_GRID;

    char* ws = (char*)d_ws;
    auto carve = [&](size_t bytes) {
        char* p = ws;
        ws += (bytes + 255) & ~(size_t)255;
        return p;
    };
    int*    cur   = (int*)carve((size_t)NB_MAX * 4);
    float*  dinv  = (float*)carve((size_t)N * 4);
    int*    pairs = (int*)carve((size_t)NB_MAX * BCAP * 4);
    __half* g1    = (__half*)carve((size_t)N * 16 * 2);
    __half* g2    = (__half*)carve((size_t)N * 16 * 2);
    (void)ws_size; (void)n_in; (void)out_size;

    k_initcur<<<1, NB_MAX, 0, stream>>>(cur);
    k_partition<<<PART_GRID, 1024, 0, stream>>>(ei, cur, pairs, E, QT);
    k_deg<<<NB, 1024, 0, stream>>>(pairs, cur, dinv, N);
    k_xform1<<<(N + 15) / 16, 256, 0, stream>>>(x, W1, dinv, g1, N);
    k_aggr1e<<<NB, 1024, 0, stream>>>(g1, pairs, cur, dinv, b1, W2, g2, N);
    k_aggr2e<<<NB, 1024, 0, stream>>>(g2, pairs, cur, dinv, b2, Wl, bl, out, N);
}